// Round 7
// baseline (1110.598 us; speedup 1.0000x reference)
//
#include <hip/hip_runtime.h>
#include <hip/hip_bf16.h>
#include <math.h>

#define BS 32
#define QN 256
#define TN 128
#define NCLS 2048
#define NTGT (BS * TN)  // 4096

// ---------------------------------------------------------------------------
// Detect whether agent_mask is stored as 1-byte bools or 4-byte int32.
// ---------------------------------------------------------------------------
__global__ void detect_mask_layout(const unsigned char* __restrict__ m, int* flag) {
    __shared__ int found;
    if (threadIdx.x == 0) found = 0;
    __syncthreads();
    int local = 0;
    for (int i = threadIdx.x; i < BS * QN; i += blockDim.x) {
        if ((i & 3) != 0 && m[i] != 0) local = 1;
    }
    if (local) atomicOr(&found, 1);
    __syncthreads();
    if (threadIdx.x == 0) *flag = found;  // 1 = byte layout, 0 = int32 layout
}

// ---------------------------------------------------------------------------
// Serial prefix: softmax per row, write ONLY the block-diagonal transposed
// entries CT[b][i][q] that the solver needs. 4 MB write instead of 128 MB.
// ---------------------------------------------------------------------------
__global__ __launch_bounds__(256) void ct_kernel(
    const float* __restrict__ logits, const int* __restrict__ labels,
    const unsigned char* __restrict__ mask_b, const int* __restrict__ use_bg,
    const int* __restrict__ layout_flag, float* __restrict__ CT) {
    __shared__ float prob_sh[NCLS];
    __shared__ float red[4];

    const int tid = threadIdx.x;
    const int bq = blockIdx.x;  // b*QN + q
    const float* row = logits + (size_t)bq * NCLS;

    const float4 xa = ((const float4*)row)[tid];
    const float4 xb = ((const float4*)row)[tid + 256];

    float m = fmaxf(fmaxf(fmaxf(xa.x, xa.y), fmaxf(xa.z, xa.w)),
                    fmaxf(fmaxf(xb.x, xb.y), fmaxf(xb.z, xb.w)));
#pragma unroll
    for (int off = 32; off >= 1; off >>= 1) m = fmaxf(m, __shfl_xor(m, off));
    if ((tid & 63) == 0) red[tid >> 6] = m;
    __syncthreads();
    m = fmaxf(fmaxf(red[0], red[1]), fmaxf(red[2], red[3]));
    __syncthreads();

    float4 ea, eb;
    ea.x = expf(xa.x - m);
    ea.y = expf(xa.y - m);
    ea.z = expf(xa.z - m);
    ea.w = expf(xa.w - m);
    eb.x = expf(xb.x - m);
    eb.y = expf(xb.y - m);
    eb.z = expf(xb.z - m);
    eb.w = expf(xb.w - m);
    float s = ((ea.x + ea.y) + (ea.z + ea.w)) + ((eb.x + eb.y) + (eb.z + eb.w));
#pragma unroll
    for (int off = 32; off >= 1; off >>= 1) s += __shfl_xor(s, off);
    if ((tid & 63) == 0) red[tid >> 6] = s;
    __syncthreads();
    s = ((red[0] + red[1]) + red[2]) + red[3];

    ((float4*)prob_sh)[tid] = make_float4(ea.x / s, ea.y / s, ea.z / s, ea.w / s);
    ((float4*)prob_sh)[tid + 256] = make_float4(eb.x / s, eb.y / s, eb.z / s, eb.w / s);

    const int ub = *use_bg;
    int am;
    if (*layout_flag)
        am = mask_b[bq];
    else
        am = ((const int*)mask_b)[bq];
    const bool zero_row = (ub == 0) && (am == 0);
    __syncthreads();

    if (tid < TN) {
        const int bb = bq >> 8;   // b
        const int q = bq & 255;   // q
        const int lab = labels[bb * TN + tid];
        CT[(size_t)bb * TN * QN + (size_t)tid * QN + q] =
            zero_row ? 0.0f : -prob_sh[lab];
    }
}

// ---------------------------------------------------------------------------
// Fallback full-C kernel (used only when workspace lacks CT room).
// ---------------------------------------------------------------------------
__global__ __launch_bounds__(256) void compute_C_kernel(
    const float* __restrict__ logits, const int* __restrict__ labels,
    const unsigned char* __restrict__ mask_b, const int* __restrict__ use_bg,
    const int* __restrict__ layout_flag, float* __restrict__ C) {
    __shared__ float prob_sh[NCLS];
    __shared__ float red[4];

    const int tid = threadIdx.x;
    const int bq = blockIdx.x;
    const float* row = logits + (size_t)bq * NCLS;

    const float4 xa = ((const float4*)row)[tid];
    const float4 xb = ((const float4*)row)[tid + 256];

    float m = fmaxf(fmaxf(fmaxf(xa.x, xa.y), fmaxf(xa.z, xa.w)),
                    fmaxf(fmaxf(xb.x, xb.y), fmaxf(xb.z, xb.w)));
#pragma unroll
    for (int off = 32; off >= 1; off >>= 1) m = fmaxf(m, __shfl_xor(m, off));
    if ((tid & 63) == 0) red[tid >> 6] = m;
    __syncthreads();
    m = fmaxf(fmaxf(red[0], red[1]), fmaxf(red[2], red[3]));
    __syncthreads();

    float4 ea, eb;
    ea.x = expf(xa.x - m);
    ea.y = expf(xa.y - m);
    ea.z = expf(xa.z - m);
    ea.w = expf(xa.w - m);
    eb.x = expf(xb.x - m);
    eb.y = expf(xb.y - m);
    eb.z = expf(xb.z - m);
    eb.w = expf(xb.w - m);
    float s = ((ea.x + ea.y) + (ea.z + ea.w)) + ((eb.x + eb.y) + (eb.z + eb.w));
#pragma unroll
    for (int off = 32; off >= 1; off >>= 1) s += __shfl_xor(s, off);
    if ((tid & 63) == 0) red[tid >> 6] = s;
    __syncthreads();
    s = ((red[0] + red[1]) + red[2]) + red[3];

    ((float4*)prob_sh)[tid] = make_float4(ea.x / s, ea.y / s, ea.z / s, ea.w / s);
    ((float4*)prob_sh)[tid + 256] = make_float4(eb.x / s, eb.y / s, eb.z / s, eb.w / s);

    const int ub = *use_bg;
    int am;
    if (*layout_flag)
        am = mask_b[bq];
    else
        am = ((const int*)mask_b)[bq];
    const bool zero_row = (ub == 0) && (am == 0);
    __syncthreads();

    float* Crow = C + (size_t)bq * NTGT;
    const int4* lab4 = (const int4*)labels;
    if (zero_row) {
        const float4 z = make_float4(0.f, 0.f, 0.f, 0.f);
#pragma unroll
        for (int k = 0; k < 4; k++) ((float4*)Crow)[tid + k * 256] = z;
    } else {
#pragma unroll
        for (int k = 0; k < 4; k++) {
            const int4 l = lab4[tid + k * 256];
            float4 o;
            o.x = -prob_sh[l.x];
            o.y = -prob_sh[l.y];
            o.z = -prob_sh[l.z];
            o.w = -prob_sh[l.w];
            ((float4*)Crow)[tid + k * 256] = o;
        }
    }
}

// ---------------------------------------------------------------------------
// Cross-lane helpers.
// ---------------------------------------------------------------------------
template <int CTRL>
__device__ __forceinline__ double dpp_mov_f64(double x) {
    union { double d; int i[2]; } a, r;
    a.d = x;
    r.i[0] = __builtin_amdgcn_update_dpp(0, a.i[0], CTRL, 0xF, 0xF, true);
    r.i[1] = __builtin_amdgcn_update_dpp(0, a.i[1], CTRL, 0xF, 0xF, true);
    return r.d;
}
// self-preserving DPP move: lanes with no source keep their own value
// (bound_ctrl=0, old=self). Required for row_bcast stages of a min tree.
template <int CTRL>
__device__ __forceinline__ double dpp_self_f64(double x) {
    union { double d; int i[2]; } a, r;
    a.d = x;
    r.i[0] = __builtin_amdgcn_update_dpp(a.i[0], a.i[0], CTRL, 0xF, 0xF, false);
    r.i[1] = __builtin_amdgcn_update_dpp(a.i[1], a.i[1], CTRL, 0xF, 0xF, false);
    return r.d;
}
__device__ __forceinline__ double read_lane_f64(double x, int srclane) {
    union { double d; int i[2]; } a, r;
    a.d = x;
    r.i[0] = __builtin_amdgcn_readlane(a.i[0], srclane);
    r.i[1] = __builtin_amdgcn_readlane(a.i[1], srclane);
    return r.d;
}
__device__ __forceinline__ int sel4(const int4& r, int slot) {
    const int a = (slot & 1) ? r.y : r.x;
    const int b = (slot & 1) ? r.w : r.z;
    return (slot & 2) ? b : a;
}

#define QUAD_XOR1   0xB1   // quad_perm(1,0,3,2)
#define QUAD_XOR2   0x4E   // quad_perm(2,3,0,1)
#define ROW_ROR4    0x124  // row_ror:4
#define ROW_ROR8    0x128  // row_ror:8
#define ROW_BCAST15 0x142  // lane15->16..31, lane47->48..63
#define ROW_BCAST31 0x143  // lane31->32..63

// ---------------------------------------------------------------------------
// Jonker-Volgenant, exact replica of reference _lsa() on the transposed
// problem (nr=TN=128 rows=targets, nc=QN=256 cols=queries). One wave/batch.
//
// Round-7 deltas vs the 918us round-6 known-good (both shave the measured
// serial chain; selection sequence bit-identical):
//
// 1. Reduce finish: 4 readlane + 3 fmin -> row_bcast:15 + row_bcast:31
//    (self-preserving DPP: old=self, bound_ctrl=0 -- no zero-poisoning) +
//    ONE readlane(63). Same multiset min, bit-exact (d in {+0, R+, INF}).
// 2. u duals: LDS -> register mirrors + readlane. ui issues right after krc
//    and completes during the ds_read flight; deletes u writes AND the last
//    per-round __syncthreads (round loop now has zero shared-state writes).
//
// Tie-mask selection (round 6): tm 4 bits/lane, 2 ballots/pop, reduce only
// when improved ca < m_d (fp edge, LT ballot) or tie set empties. Register
// augment walk (round 6). [r1/r4: do NOT retry LDS cost-row prefetch; r5:
// do NOT add per-pop ballots beyond 2.]
// ---------------------------------------------------------------------------
__device__ __forceinline__ void lsa_solve(
    const float* __restrict__ C, const float* __restrict__ CT,
    float* __restrict__ rows_out, float* __restrict__ cols_out,
    int b, int lane,
    float* cost_sh, int* col4row_sh) {
    const int j0 = lane * 4;

    double v0 = 0.0, v1 = 0.0, v2 = 0.0, v3 = 0.0;  // col duals (owned cols)
    double u0 = 0.0, u1 = 0.0;                      // row duals (owned rows 2l,2l+1)
    int4 rc = make_int4(-1, -1, -1, -1);            // row4col (owned cols)
    int c0 = -1, c1 = -1;                           // col4row (owned rows)

    if (CT) {
        const float4* src = (const float4*)(CT + (size_t)b * TN * QN);
        float4* dst = (float4*)cost_sh;
#pragma unroll 8
        for (int it = 0; it < TN * QN / 4 / 64; it++) {
            const int idx = it * 64 + lane;
            dst[idx] = src[idx];
        }
    } else {
        // fallback: scattered gather straight from C (one-time staging cost)
        const float* cbsrc = C + (size_t)b * QN * NTGT + b * TN;
        for (int it = 0; it < 512; it++) {
            const int j = it >> 1;
            const int i = lane + 64 * (it & 1);
            cost_sh[i * QN + j] = cbsrc[(size_t)j * NTGT + i];
        }
    }
    __syncthreads();

    for (int cur = 0; cur < TN; cur++) {
        double dv0 = INFINITY, dv1 = INFINITY, dv2 = INFINITY, dv3 = INFINITY;
        double dm0 = INFINITY, dm1 = INFINITY, dm2 = INFINITY, dm3 = INFINITY;
        double du0 = 0.0, du1 = 0.0;
        int sc = 0, sr = 0;
        int p0 = 0, p1 = 0, p2 = 0, p3 = 0;
        if (lane == (cur >> 1)) sr = 1 << (cur & 1);  // SR[cur]=1

        int i = cur;
        double m_d = 0.0;
        double ui = read_lane_f64((cur & 1) ? u1 : u0, cur >> 1);
        int tm = 0;  // tie mask: owned cols with d == m_d, not SC'd
        int sink;

        while (true) {
            const float4 cc = *(const float4*)(cost_sh + i * QN + j0);

            // numpy order: ((minVal + cost) - u[i]) - v[j]; strict r < d
            const double ca0 = ((m_d + (double)cc.x) - ui) - v0;
            const double ca1 = ((m_d + (double)cc.y) - ui) - v1;
            const double ca2 = ((m_d + (double)cc.z) - ui) - v2;
            const double ca3 = ((m_d + (double)cc.w) - ui) - v3;
            const bool i0 = !(sc & 1) && (ca0 < dv0);
            const bool i1 = !(sc & 2) && (ca1 < dv1);
            const bool i2 = !(sc & 4) && (ca2 < dv2);
            const bool i3 = !(sc & 8) && (ca3 < dv3);
            if (i0) { dv0 = ca0; dm0 = ca0; p0 = i; }
            if (i1) { dv1 = ca1; dm1 = ca1; p1 = i; }
            if (i2) { dv2 = ca2; dm2 = ca2; p2 = i; }
            if (i3) { dv3 = ca3; dm3 = ca3; p3 = i; }

            // lane-local tie maintenance (VALU, 2 ballots total per pop)
            const bool lt_any = (i0 && ca0 < m_d) || (i1 && ca1 < m_d) ||
                                (i2 && ca2 < m_d) || (i3 && ca3 < m_d);
            int tmn = tm;
            if (i0 && ca0 == m_d) tmn |= 1;
            if (i1 && ca1 == m_d) tmn |= 2;
            if (i2 && ca2 == m_d) tmn |= 4;
            if (i3 && ca3 == m_d) tmn |= 8;

            const unsigned long long LT = __ballot(lt_any);
            unsigned long long W = __ballot(tmn != 0);

            if (LT != 0ull || W == 0ull) {
                // full argmin: f64 min tree, bcast finish, single readlane
                double lm = fmin(fmin(dm0, dm1), fmin(dm2, dm3));
                lm = fmin(lm, dpp_mov_f64<QUAD_XOR1>(lm));
                lm = fmin(lm, dpp_mov_f64<QUAD_XOR2>(lm));
                lm = fmin(lm, dpp_mov_f64<ROW_ROR4>(lm));
                lm = fmin(lm, dpp_mov_f64<ROW_ROR8>(lm));
                lm = fmin(lm, dpp_self_f64<ROW_BCAST15>(lm));
                lm = fmin(lm, dpp_self_f64<ROW_BCAST31>(lm));
                m_d = read_lane_f64(lm, 63);
                // rebuild tie mask (dm=INF for SC'd -> excluded automatically)
                tmn = (dm0 == m_d ? 1 : 0) | (dm1 == m_d ? 2 : 0) |
                      (dm2 == m_d ? 4 : 0) | (dm3 == m_d ? 8 : 0);
                W = __ballot(tmn != 0);
            }

            // pick lowest column among ties: lowest lane, then lowest slot
            const int owner = __ffsll((unsigned long long)W) - 1;
            const int sm = __builtin_amdgcn_readlane(tmn, owner);
            const int slot = __ffs(sm) - 1;
            const int jmin = (owner << 2) + slot;

            if (lane == owner) {  // mark SC, freeze dm, clear tie bit
                sc |= 1 << slot;
                tmn &= ~(1 << slot);
                if (slot == 0) dm0 = INFINITY;
                else if (slot == 1) dm1 = INFINITY;
                else if (slot == 2) dm2 = INFINITY;
                else dm3 = INFINITY;
            }
            tm = tmn;

            // krc = row4col[jmin] via register mirror + readlane
            const int krc = __builtin_amdgcn_readlane(sel4(rc, slot), owner);
            if (krc < 0) { sink = jmin; break; }

            // ui via readlane: issues now, completes under the ds_read flight
            ui = read_lane_f64((krc & 1) ? u1 : u0, krc >> 1);

            // SR/du row mirrors
            if (lane == (krc >> 1)) {
                if (krc & 1) { du1 = m_d; sr |= 2; }
                else { du0 = m_d; sr |= 1; }
            }
            i = krc;
        }

        // ---- round end (registers only; zero barriers in the round loop) ----
        // dual updates (scipy _lsap_body); dv/du frozen at selection time
        if (sc & 1) v0 -= m_d - dv0;
        if (sc & 2) v1 -= m_d - dv1;
        if (sc & 4) v2 -= m_d - dv2;
        if (sc & 8) v3 -= m_d - dv3;
        if (sr & 1) u0 += (2 * lane == cur) ? m_d : (m_d - du0);
        if (sr & 2) u1 += (2 * lane + 1 == cur) ? m_d : (m_d - du1);

        // augment along shortest path: all lanes walk redundantly (uniform),
        // each updating its own register mirrors via readlane broadcasts
        int j = sink;
        while (true) {
            const int sl = j & 3;
            const int ow = j >> 2;
            const int pa = (sl & 1) ? p1 : p0;
            const int pb = (sl & 1) ? p3 : p2;
            const int pi = __builtin_amdgcn_readlane((sl & 2) ? pb : pa, ow);
            if (lane == ow) {  // row4col[j] = pi
                if (sl == 0) rc.x = pi;
                else if (sl == 1) rc.y = pi;
                else if (sl == 2) rc.z = pi;
                else rc.w = pi;
            }
            const int nj = __builtin_amdgcn_readlane((pi & 1) ? c1 : c0, pi >> 1);
            if (lane == (pi >> 1)) {  // col4row[pi] = j
                if (pi & 1) c1 = j;
                else c0 = j;
            }
            j = nj;
            if (pi == cur) break;
        }
    }

    // publish col4row once for the rank pass
    col4row_sh[2 * lane] = c0;
    col4row_sh[2 * lane + 1] = c1;
    __syncthreads();

    // transposed output: rank by col4row value (values distinct)
#pragma unroll
    for (int t = 0; t < 2; t++) {
        const int ii = lane + 64 * t;
        const int myv = col4row_sh[ii];
        int rank = 0;
        for (int t2 = 0; t2 < TN; t2++) rank += (col4row_sh[t2] < myv) ? 1 : 0;
        rows_out[b * TN + rank] = (float)myv;
        cols_out[b * TN + rank] = (float)ii;
    }
}

// ---------------------------------------------------------------------------
// Standalone lsa kernel (fallback path).
// ---------------------------------------------------------------------------
__global__ __launch_bounds__(64) void lsa_kernel(const float* __restrict__ C,
                                                 const float* __restrict__ CT,
                                                 float* __restrict__ rows_out,
                                                 float* __restrict__ cols_out) {
    __shared__ float cost_sh[TN * QN];  // 128 KB
    __shared__ int col4row_sh[TN];
    lsa_solve(C, CT, rows_out, cols_out, blockIdx.x, threadIdx.x,
              cost_sh, col4row_sh);
}

// ---------------------------------------------------------------------------
// Fused kernel: blocks 0..BS-1 run the solver (1 wave, 1 CU each, LDS-pinned
// so no filler can co-reside: 2x~129KB > 160KB). Blocks BS.. are fillers
// that produce the 128 MB C output on the other ~224 CUs, fully hidden under
// the solve. No inter-block deps: disjoint outputs, read-only inputs.
// ---------------------------------------------------------------------------
__global__ __launch_bounds__(64) void fused_kernel(
    const float* __restrict__ logits, const int* __restrict__ labels,
    const unsigned char* __restrict__ mask_b, const int* __restrict__ use_bg,
    const int* __restrict__ layout_flag, const float* __restrict__ CT,
    float* __restrict__ C, float* __restrict__ rows_out,
    float* __restrict__ cols_out) {
    __shared__ float cost_sh[TN * QN];  // solver: cost matrix; filler: prob scratch
    __shared__ int col4row_sh[TN];

    const int lane = threadIdx.x;

    if (blockIdx.x >= BS) {
        // ---------------- filler: one row of C per block, wave-local ----------------
        const int bq = blockIdx.x - BS;
        const float* row = logits + (size_t)bq * NCLS;

        float4 x[8];
#pragma unroll
        for (int k = 0; k < 8; k++) x[k] = ((const float4*)row)[lane + 64 * k];

        float m = -INFINITY;
#pragma unroll
        for (int k = 0; k < 8; k++)
            m = fmaxf(m, fmaxf(fmaxf(x[k].x, x[k].y), fmaxf(x[k].z, x[k].w)));
#pragma unroll
        for (int off = 32; off >= 1; off >>= 1) m = fmaxf(m, __shfl_xor(m, off));

        float s = 0.f;
        float4 e[8];
#pragma unroll
        for (int k = 0; k < 8; k++) {
            e[k].x = expf(x[k].x - m);
            e[k].y = expf(x[k].y - m);
            e[k].z = expf(x[k].z - m);
            e[k].w = expf(x[k].w - m);
            s += ((e[k].x + e[k].y) + (e[k].z + e[k].w));
        }
#pragma unroll
        for (int off = 32; off >= 1; off >>= 1) s += __shfl_xor(s, off);

        float* prob = cost_sh;  // 8 KB scratch
#pragma unroll
        for (int k = 0; k < 8; k++)
            ((float4*)prob)[lane + 64 * k] =
                make_float4(e[k].x / s, e[k].y / s, e[k].z / s, e[k].w / s);

        const int ub = *use_bg;
        int am;
        if (*layout_flag)
            am = mask_b[bq];
        else
            am = ((const int*)mask_b)[bq];
        const bool zero_row = (ub == 0) && (am == 0);
        __syncthreads();  // single wave: cheap lgkmcnt drain + barrier

        float* Crow = C + (size_t)bq * NTGT;
        const int4* lab4 = (const int4*)labels;
        if (zero_row) {
            const float4 z = make_float4(0.f, 0.f, 0.f, 0.f);
#pragma unroll
            for (int k = 0; k < 16; k++) ((float4*)Crow)[lane + 64 * k] = z;
        } else {
#pragma unroll
            for (int k = 0; k < 16; k++) {
                const int4 l = lab4[lane + 64 * k];
                ((float4*)Crow)[lane + 64 * k] =
                    make_float4(-prob[l.x], -prob[l.y], -prob[l.z], -prob[l.w]);
            }
        }
        return;
    }

    // ---------------- solver ----------------
    lsa_solve(nullptr, CT, rows_out, cols_out, blockIdx.x, lane,
              cost_sh, col4row_sh);
}

extern "C" void kernel_launch(void* const* d_in, const int* in_sizes, int n_in,
                              void* d_out, int out_size, void* d_ws, size_t ws_size,
                              hipStream_t stream) {
    const float* logits = (const float*)d_in[0];                  // [32,256,2048] f32
    const int* labels = (const int*)d_in[1];                      // [32,128] i32
    const unsigned char* mask_b = (const unsigned char*)d_in[2];  // [32,256] bool/i32
    const int* use_bg = (const int*)d_in[3];                      // scalar

    float* C = (float*)d_out;  // 32*256*4096
    float* rows_out = C + (size_t)BS * QN * NTGT;
    float* cols_out = rows_out + BS * TN;

    int* flag = (int*)d_ws;
    const size_t ct_off = 4096;
    const size_t ct_bytes = (size_t)BS * TN * QN * sizeof(float);  // 4 MB
    const bool useCT = ws_size >= ct_off + ct_bytes;
    float* CT = useCT ? (float*)((char*)d_ws + ct_off) : nullptr;

    detect_mask_layout<<<1, 256, 0, stream>>>(mask_b, flag);
    if (useCT) {
        // minimal serial prefix (4 MB CT), then solver + hidden C production
        ct_kernel<<<BS * QN, 256, 0, stream>>>(logits, labels, mask_b, use_bg, flag, CT);
        fused_kernel<<<BS + BS * QN, 64, 0, stream>>>(logits, labels, mask_b, use_bg,
                                                      flag, CT, C, rows_out, cols_out);
    } else {
        compute_C_kernel<<<BS * QN, 256, 0, stream>>>(logits, labels, mask_b, use_bg,
                                                      flag, C);
        lsa_kernel<<<BS, 64, 0, stream>>>(C, nullptr, rows_out, cols_out);
    }
}

// Round 8
// 1056.846 us; speedup vs baseline: 1.0509x; 1.0509x over previous
//
#include <hip/hip_runtime.h>
#include <hip/hip_bf16.h>
#include <math.h>

#define BS 32
#define QN 256
#define TN 128
#define NCLS 2048
#define NTGT (BS * TN)  // 4096

// ---------------------------------------------------------------------------
// Detect whether agent_mask is stored as 1-byte bools or 4-byte int32.
// ---------------------------------------------------------------------------
__global__ void detect_mask_layout(const unsigned char* __restrict__ m, int* flag) {
    __shared__ int found;
    if (threadIdx.x == 0) found = 0;
    __syncthreads();
    int local = 0;
    for (int i = threadIdx.x; i < BS * QN; i += blockDim.x) {
        if ((i & 3) != 0 && m[i] != 0) local = 1;
    }
    if (local) atomicOr(&found, 1);
    __syncthreads();
    if (threadIdx.x == 0) *flag = found;  // 1 = byte layout, 0 = int32 layout
}

// ---------------------------------------------------------------------------
// Serial prefix: softmax per row, write ONLY the block-diagonal transposed
// entries CT[b][i][q] that the solver needs. 4 MB write instead of 128 MB.
// ---------------------------------------------------------------------------
__global__ __launch_bounds__(256) void ct_kernel(
    const float* __restrict__ logits, const int* __restrict__ labels,
    const unsigned char* __restrict__ mask_b, const int* __restrict__ use_bg,
    const int* __restrict__ layout_flag, float* __restrict__ CT) {
    __shared__ float prob_sh[NCLS];
    __shared__ float red[4];

    const int tid = threadIdx.x;
    const int bq = blockIdx.x;  // b*QN + q
    const float* row = logits + (size_t)bq * NCLS;

    const float4 xa = ((const float4*)row)[tid];
    const float4 xb = ((const float4*)row)[tid + 256];

    float m = fmaxf(fmaxf(fmaxf(xa.x, xa.y), fmaxf(xa.z, xa.w)),
                    fmaxf(fmaxf(xb.x, xb.y), fmaxf(xb.z, xb.w)));
#pragma unroll
    for (int off = 32; off >= 1; off >>= 1) m = fmaxf(m, __shfl_xor(m, off));
    if ((tid & 63) == 0) red[tid >> 6] = m;
    __syncthreads();
    m = fmaxf(fmaxf(red[0], red[1]), fmaxf(red[2], red[3]));
    __syncthreads();

    float4 ea, eb;
    ea.x = expf(xa.x - m);
    ea.y = expf(xa.y - m);
    ea.z = expf(xa.z - m);
    ea.w = expf(xa.w - m);
    eb.x = expf(xb.x - m);
    eb.y = expf(xb.y - m);
    eb.z = expf(xb.z - m);
    eb.w = expf(xb.w - m);
    float s = ((ea.x + ea.y) + (ea.z + ea.w)) + ((eb.x + eb.y) + (eb.z + eb.w));
#pragma unroll
    for (int off = 32; off >= 1; off >>= 1) s += __shfl_xor(s, off);
    if ((tid & 63) == 0) red[tid >> 6] = s;
    __syncthreads();
    s = ((red[0] + red[1]) + red[2]) + red[3];

    ((float4*)prob_sh)[tid] = make_float4(ea.x / s, ea.y / s, ea.z / s, ea.w / s);
    ((float4*)prob_sh)[tid + 256] = make_float4(eb.x / s, eb.y / s, eb.z / s, eb.w / s);

    const int ub = *use_bg;
    int am;
    if (*layout_flag)
        am = mask_b[bq];
    else
        am = ((const int*)mask_b)[bq];
    const bool zero_row = (ub == 0) && (am == 0);
    __syncthreads();

    if (tid < TN) {
        const int bb = bq >> 8;   // b
        const int q = bq & 255;   // q
        const int lab = labels[bb * TN + tid];
        CT[(size_t)bb * TN * QN + (size_t)tid * QN + q] =
            zero_row ? 0.0f : -prob_sh[lab];
    }
}

// ---------------------------------------------------------------------------
// Fallback full-C kernel (used only when workspace lacks CT room).
// ---------------------------------------------------------------------------
__global__ __launch_bounds__(256) void compute_C_kernel(
    const float* __restrict__ logits, const int* __restrict__ labels,
    const unsigned char* __restrict__ mask_b, const int* __restrict__ use_bg,
    const int* __restrict__ layout_flag, float* __restrict__ C) {
    __shared__ float prob_sh[NCLS];
    __shared__ float red[4];

    const int tid = threadIdx.x;
    const int bq = blockIdx.x;
    const float* row = logits + (size_t)bq * NCLS;

    const float4 xa = ((const float4*)row)[tid];
    const float4 xb = ((const float4*)row)[tid + 256];

    float m = fmaxf(fmaxf(fmaxf(xa.x, xa.y), fmaxf(xa.z, xa.w)),
                    fmaxf(fmaxf(xb.x, xb.y), fmaxf(xb.z, xb.w)));
#pragma unroll
    for (int off = 32; off >= 1; off >>= 1) m = fmaxf(m, __shfl_xor(m, off));
    if ((tid & 63) == 0) red[tid >> 6] = m;
    __syncthreads();
    m = fmaxf(fmaxf(red[0], red[1]), fmaxf(red[2], red[3]));
    __syncthreads();

    float4 ea, eb;
    ea.x = expf(xa.x - m);
    ea.y = expf(xa.y - m);
    ea.z = expf(xa.z - m);
    ea.w = expf(xa.w - m);
    eb.x = expf(xb.x - m);
    eb.y = expf(xb.y - m);
    eb.z = expf(xb.z - m);
    eb.w = expf(xb.w - m);
    float s = ((ea.x + ea.y) + (ea.z + ea.w)) + ((eb.x + eb.y) + (eb.z + eb.w));
#pragma unroll
    for (int off = 32; off >= 1; off >>= 1) s += __shfl_xor(s, off);
    if ((tid & 63) == 0) red[tid >> 6] = s;
    __syncthreads();
    s = ((red[0] + red[1]) + red[2]) + red[3];

    ((float4*)prob_sh)[tid] = make_float4(ea.x / s, ea.y / s, ea.z / s, ea.w / s);
    ((float4*)prob_sh)[tid + 256] = make_float4(eb.x / s, eb.y / s, eb.z / s, eb.w / s);

    const int ub = *use_bg;
    int am;
    if (*layout_flag)
        am = mask_b[bq];
    else
        am = ((const int*)mask_b)[bq];
    const bool zero_row = (ub == 0) && (am == 0);
    __syncthreads();

    float* Crow = C + (size_t)bq * NTGT;
    const int4* lab4 = (const int4*)labels;
    if (zero_row) {
        const float4 z = make_float4(0.f, 0.f, 0.f, 0.f);
#pragma unroll
        for (int k = 0; k < 4; k++) ((float4*)Crow)[tid + k * 256] = z;
    } else {
#pragma unroll
        for (int k = 0; k < 4; k++) {
            const int4 l = lab4[tid + k * 256];
            float4 o;
            o.x = -prob_sh[l.x];
            o.y = -prob_sh[l.y];
            o.z = -prob_sh[l.z];
            o.w = -prob_sh[l.w];
            ((float4*)Crow)[tid + k * 256] = o;
        }
    }
}

// ---------------------------------------------------------------------------
// Cross-lane helpers.
// ---------------------------------------------------------------------------
template <int CTRL>
__device__ __forceinline__ double dpp_mov_f64(double x) {
    union { double d; int i[2]; } a, r;
    a.d = x;
    r.i[0] = __builtin_amdgcn_update_dpp(0, a.i[0], CTRL, 0xF, 0xF, true);
    r.i[1] = __builtin_amdgcn_update_dpp(0, a.i[1], CTRL, 0xF, 0xF, true);
    return r.d;
}
__device__ __forceinline__ double read_lane_f64(double x, int srclane) {
    union { double d; int i[2]; } a, r;
    a.d = x;
    r.i[0] = __builtin_amdgcn_readlane(a.i[0], srclane);
    r.i[1] = __builtin_amdgcn_readlane(a.i[1], srclane);
    return r.d;
}

#define QUAD_XOR1 0xB1   // quad_perm(1,0,3,2)
#define QUAD_XOR2 0x4E   // quad_perm(2,3,0,1)
#define ROW_ROR4  0x124  // row_ror:4
#define ROW_ROR8  0x128  // row_ror:8

// ---------------------------------------------------------------------------
// Jonker-Volgenant, exact replica of reference _lsa() on the transposed
// problem (nr=TN=128 rows=targets, nc=QN=256 cols=queries). One wave/batch.
//
// Base = round-6 known-good (918us): tie-mask selection (tm 4 bits/lane,
// 2 ballots/pop, reduce only when improved ca < m_d or tie set empties),
// register augment walk, u in LDS (read overlaps cost-row read), 4-readlane
// + 3-fmin reduce finish, one __syncthreads per round.
//
// Round-8 delta (ONE change): row4col register mirror int4 -> PACKED 32-bit
// pk (byte b = rc[col 4l+b]+1; rc in [-1,127] -> byte in [0,128]). Selection
// chain loses the dependent cndmask-select + second dependent readlane:
//   old: readlane(tmn)->ffs->cndmask sel4->readlane(rc_sel) (~44cy)
//   new: {readlane(tmn) || readlane(pk)} parallel ->ffs->SALU shift/mask (~34cy)
// pk is round-constant during pops (updated only in the augment walk, off
// the pop chain). Pure integer repacking -- selection sequence bit-identical.
//
// [r1/r4: do NOT retry LDS cost-row prefetch (compiler drain / mispredict
//  cost). r5: do NOT exceed 2 ballots/pop. r7: do NOT add dependent DPP
//  bcast stages to the reduce finish; do NOT move u to readlane mirrors --
//  bundle measured +25us vs r6.]
// ---------------------------------------------------------------------------
__device__ __forceinline__ void lsa_solve(
    const float* __restrict__ C, const float* __restrict__ CT,
    float* __restrict__ rows_out, float* __restrict__ cols_out,
    int b, int lane,
    float* cost_sh, double* u_sh, int* col4row_sh) {
    const int j0 = lane * 4;

    u_sh[lane] = 0.0;
    u_sh[lane + 64] = 0.0;

    double v0 = 0.0, v1 = 0.0, v2 = 0.0, v3 = 0.0;  // col duals (owned cols)
    double u0 = 0.0, u1 = 0.0;                      // row duals (owned rows)
    unsigned pk = 0u;       // packed row4col+1 (byte per owned col); 0 = -1
    int c0 = -1, c1 = -1;   // col4row (owned rows)

    if (CT) {
        const float4* src = (const float4*)(CT + (size_t)b * TN * QN);
        float4* dst = (float4*)cost_sh;
#pragma unroll 8
        for (int it = 0; it < TN * QN / 4 / 64; it++) {
            const int idx = it * 64 + lane;
            dst[idx] = src[idx];
        }
    } else {
        // fallback: scattered gather straight from C (one-time staging cost)
        const float* cbsrc = C + (size_t)b * QN * NTGT + b * TN;
        for (int it = 0; it < 512; it++) {
            const int j = it >> 1;
            const int i = lane + 64 * (it & 1);
            cost_sh[i * QN + j] = cbsrc[(size_t)j * NTGT + i];
        }
    }
    __syncthreads();

    for (int cur = 0; cur < TN; cur++) {
        double dv0 = INFINITY, dv1 = INFINITY, dv2 = INFINITY, dv3 = INFINITY;
        double dm0 = INFINITY, dm1 = INFINITY, dm2 = INFINITY, dm3 = INFINITY;
        double du0 = 0.0, du1 = 0.0;
        int sc = 0, sr = 0;
        int p0 = 0, p1 = 0, p2 = 0, p3 = 0;
        if (lane == (cur >> 1)) sr = 1 << (cur & 1);  // SR[cur]=1

        int i = cur;
        double m_d = 0.0;
        int tm = 0;  // tie mask: owned cols with d == m_d, not SC'd
        int sink;

        while (true) {
            const float4 cc = *(const float4*)(cost_sh + i * QN + j0);
            const double ui = u_sh[i];  // broadcast read (overlaps cc read)

            // numpy order: ((minVal + cost) - u[i]) - v[j]; strict r < d
            const double ca0 = ((m_d + (double)cc.x) - ui) - v0;
            const double ca1 = ((m_d + (double)cc.y) - ui) - v1;
            const double ca2 = ((m_d + (double)cc.z) - ui) - v2;
            const double ca3 = ((m_d + (double)cc.w) - ui) - v3;
            const bool i0 = !(sc & 1) && (ca0 < dv0);
            const bool i1 = !(sc & 2) && (ca1 < dv1);
            const bool i2 = !(sc & 4) && (ca2 < dv2);
            const bool i3 = !(sc & 8) && (ca3 < dv3);
            if (i0) { dv0 = ca0; dm0 = ca0; p0 = i; }
            if (i1) { dv1 = ca1; dm1 = ca1; p1 = i; }
            if (i2) { dv2 = ca2; dm2 = ca2; p2 = i; }
            if (i3) { dv3 = ca3; dm3 = ca3; p3 = i; }

            // lane-local tie maintenance (VALU, 2 ballots total per pop)
            const bool lt_any = (i0 && ca0 < m_d) || (i1 && ca1 < m_d) ||
                                (i2 && ca2 < m_d) || (i3 && ca3 < m_d);
            int tmn = tm;
            if (i0 && ca0 == m_d) tmn |= 1;
            if (i1 && ca1 == m_d) tmn |= 2;
            if (i2 && ca2 == m_d) tmn |= 4;
            if (i3 && ca3 == m_d) tmn |= 8;

            const unsigned long long LT = __ballot(lt_any);
            unsigned long long W = __ballot(tmn != 0);

            if (LT != 0ull || W == 0ull) {
                // full argmin: f64 min tree (4 DPP row stages + readlane finish)
                double lm = fmin(fmin(dm0, dm1), fmin(dm2, dm3));
                lm = fmin(lm, dpp_mov_f64<QUAD_XOR1>(lm));
                lm = fmin(lm, dpp_mov_f64<QUAD_XOR2>(lm));
                lm = fmin(lm, dpp_mov_f64<ROW_ROR4>(lm));
                lm = fmin(lm, dpp_mov_f64<ROW_ROR8>(lm));
                const double r0 = read_lane_f64(lm, 0);
                const double r1 = read_lane_f64(lm, 16);
                const double r2 = read_lane_f64(lm, 32);
                const double r3 = read_lane_f64(lm, 48);
                m_d = fmin(fmin(r0, r1), fmin(r2, r3));
                // rebuild tie mask (dm=INF for SC'd -> excluded automatically)
                tmn = (dm0 == m_d ? 1 : 0) | (dm1 == m_d ? 2 : 0) |
                      (dm2 == m_d ? 4 : 0) | (dm3 == m_d ? 8 : 0);
                W = __ballot(tmn != 0);
            }

            // pick lowest column among ties: lowest lane, then lowest slot.
            // The two readlanes are independent -> issue back-to-back.
            const int owner = __ffsll((unsigned long long)W) - 1;
            const int sm = __builtin_amdgcn_readlane(tmn, owner);
            const unsigned pkv = (unsigned)__builtin_amdgcn_readlane((int)pk, owner);
            const int slot = __ffs(sm) - 1;
            const int jmin = (owner << 2) + slot;
            const int krc = (int)((pkv >> (slot * 8)) & 0xffu) - 1;

            if (lane == owner) {  // mark SC, freeze dm, clear tie bit
                sc |= 1 << slot;
                tmn &= ~(1 << slot);
                if (slot == 0) dm0 = INFINITY;
                else if (slot == 1) dm1 = INFINITY;
                else if (slot == 2) dm2 = INFINITY;
                else dm3 = INFINITY;
            }
            tm = tmn;

            if (krc < 0) { sink = jmin; break; }

            // SR/du row mirrors
            if (lane == (krc >> 1)) {
                if (krc & 1) { du1 = m_d; sr |= 2; }
                else { du0 = m_d; sr |= 1; }
            }
            i = krc;
        }

        // ---- round end ----
        // dual updates (scipy _lsap_body); dv/du frozen at selection time
        if (sc & 1) v0 -= m_d - dv0;
        if (sc & 2) v1 -= m_d - dv1;
        if (sc & 4) v2 -= m_d - dv2;
        if (sc & 8) v3 -= m_d - dv3;
        if (sr & 1) u0 += (2 * lane == cur) ? m_d : (m_d - du0);
        if (sr & 2) u1 += (2 * lane + 1 == cur) ? m_d : (m_d - du1);
        u_sh[2 * lane] = u0;
        u_sh[2 * lane + 1] = u1;

        // augment along shortest path: all lanes walk redundantly (uniform),
        // each updating its own register mirrors via readlane broadcasts.
        // pk (packed row4col) is updated HERE only -- off the pop chain.
        int j = sink;
        while (true) {
            const int sl = j & 3;
            const int ow = j >> 2;
            const int pa = (sl & 1) ? p1 : p0;
            const int pb = (sl & 1) ? p3 : p2;
            const int pi = __builtin_amdgcn_readlane((sl & 2) ? pb : pa, ow);
            if (lane == ow) {  // row4col[j] = pi  (packed byte insert)
                const int sh = sl * 8;
                pk = (pk & ~(0xffu << sh)) | ((unsigned)(pi + 1) << sh);
            }
            const int nj = __builtin_amdgcn_readlane((pi & 1) ? c1 : c0, pi >> 1);
            if (lane == (pi >> 1)) {  // col4row[pi] = j
                if (pi & 1) c1 = j;
                else c0 = j;
            }
            j = nj;
            if (pi == cur) break;
        }
        __syncthreads();  // u visible for next round (single wave: cheap)
    }

    // publish col4row once for the rank pass
    col4row_sh[2 * lane] = c0;
    col4row_sh[2 * lane + 1] = c1;
    __syncthreads();

    // transposed output: rank by col4row value (values distinct)
#pragma unroll
    for (int t = 0; t < 2; t++) {
        const int ii = lane + 64 * t;
        const int myv = col4row_sh[ii];
        int rank = 0;
        for (int t2 = 0; t2 < TN; t2++) rank += (col4row_sh[t2] < myv) ? 1 : 0;
        rows_out[b * TN + rank] = (float)myv;
        cols_out[b * TN + rank] = (float)ii;
    }
}

// ---------------------------------------------------------------------------
// Standalone lsa kernel (fallback path).
// ---------------------------------------------------------------------------
__global__ __launch_bounds__(64) void lsa_kernel(const float* __restrict__ C,
                                                 const float* __restrict__ CT,
                                                 float* __restrict__ rows_out,
                                                 float* __restrict__ cols_out) {
    __shared__ float cost_sh[TN * QN];  // 128 KB
    __shared__ double u_sh[TN];
    __shared__ int col4row_sh[TN];
    lsa_solve(C, CT, rows_out, cols_out, blockIdx.x, threadIdx.x,
              cost_sh, u_sh, col4row_sh);
}

// ---------------------------------------------------------------------------
// Fused kernel: blocks 0..BS-1 run the solver (1 wave, 1 CU each, LDS-pinned
// so no filler can co-reside: 2x~130KB > 160KB). Blocks BS.. are fillers
// that produce the 128 MB C output on the other ~224 CUs, fully hidden under
// the solve. No inter-block deps: disjoint outputs, read-only inputs.
// ---------------------------------------------------------------------------
__global__ __launch_bounds__(64) void fused_kernel(
    const float* __restrict__ logits, const int* __restrict__ labels,
    const unsigned char* __restrict__ mask_b, const int* __restrict__ use_bg,
    const int* __restrict__ layout_flag, const float* __restrict__ CT,
    float* __restrict__ C, float* __restrict__ rows_out,
    float* __restrict__ cols_out) {
    __shared__ float cost_sh[TN * QN];  // solver: cost matrix; filler: prob scratch
    __shared__ double u_sh[TN];
    __shared__ int col4row_sh[TN];

    const int lane = threadIdx.x;

    if (blockIdx.x >= BS) {
        // ---------------- filler: one row of C per block, wave-local ----------------
        const int bq = blockIdx.x - BS;
        const float* row = logits + (size_t)bq * NCLS;

        float4 x[8];
#pragma unroll
        for (int k = 0; k < 8; k++) x[k] = ((const float4*)row)[lane + 64 * k];

        float m = -INFINITY;
#pragma unroll
        for (int k = 0; k < 8; k++)
            m = fmaxf(m, fmaxf(fmaxf(x[k].x, x[k].y), fmaxf(x[k].z, x[k].w)));
#pragma unroll
        for (int off = 32; off >= 1; off >>= 1) m = fmaxf(m, __shfl_xor(m, off));

        float s = 0.f;
        float4 e[8];
#pragma unroll
        for (int k = 0; k < 8; k++) {
            e[k].x = expf(x[k].x - m);
            e[k].y = expf(x[k].y - m);
            e[k].z = expf(x[k].z - m);
            e[k].w = expf(x[k].w - m);
            s += ((e[k].x + e[k].y) + (e[k].z + e[k].w));
        }
#pragma unroll
        for (int off = 32; off >= 1; off >>= 1) s += __shfl_xor(s, off);

        float* prob = cost_sh;  // 8 KB scratch
#pragma unroll
        for (int k = 0; k < 8; k++)
            ((float4*)prob)[lane + 64 * k] =
                make_float4(e[k].x / s, e[k].y / s, e[k].z / s, e[k].w / s);

        const int ub = *use_bg;
        int am;
        if (*layout_flag)
            am = mask_b[bq];
        else
            am = ((const int*)mask_b)[bq];
        const bool zero_row = (ub == 0) && (am == 0);
        __syncthreads();  // single wave: cheap lgkmcnt drain + barrier

        float* Crow = C + (size_t)bq * NTGT;
        const int4* lab4 = (const int4*)labels;
        if (zero_row) {
            const float4 z = make_float4(0.f, 0.f, 0.f, 0.f);
#pragma unroll
            for (int k = 0; k < 16; k++) ((float4*)Crow)[lane + 64 * k] = z;
        } else {
#pragma unroll
            for (int k = 0; k < 16; k++) {
                const int4 l = lab4[lane + 64 * k];
                ((float4*)Crow)[lane + 64 * k] =
                    make_float4(-prob[l.x], -prob[l.y], -prob[l.z], -prob[l.w]);
            }
        }
        return;
    }

    // ---------------- solver ----------------
    lsa_solve(nullptr, CT, rows_out, cols_out, blockIdx.x, lane,
              cost_sh, u_sh, col4row_sh);
}

extern "C" void kernel_launch(void* const* d_in, const int* in_sizes, int n_in,
                              void* d_out, int out_size, void* d_ws, size_t ws_size,
                              hipStream_t stream) {
    const float* logits = (const float*)d_in[0];                  // [32,256,2048] f32
    const int* labels = (const int*)d_in[1];                      // [32,128] i32
    const unsigned char* mask_b = (const unsigned char*)d_in[2];  // [32,256] bool/i32
    const int* use_bg = (const int*)d_in[3];                      // scalar

    float* C = (float*)d_out;  // 32*256*4096
    float* rows_out = C + (size_t)BS * QN * NTGT;
    float* cols_out = rows_out + BS * TN;

    int* flag = (int*)d_ws;
    const size_t ct_off = 4096;
    const size_t ct_bytes = (size_t)BS * TN * QN * sizeof(float);  // 4 MB
    const bool useCT = ws_size >= ct_off + ct_bytes;
    float* CT = useCT ? (float*)((char*)d_ws + ct_off) : nullptr;

    detect_mask_layout<<<1, 256, 0, stream>>>(mask_b, flag);
    if (useCT) {
        // minimal serial prefix (4 MB CT), then solver + hidden C production
        ct_kernel<<<BS * QN, 256, 0, stream>>>(logits, labels, mask_b, use_bg, flag, CT);
        fused_kernel<<<BS + BS * QN, 64, 0, stream>>>(logits, labels, mask_b, use_bg,
                                                      flag, CT, C, rows_out, cols_out);
    } else {
        compute_C_kernel<<<BS * QN, 256, 0, stream>>>(logits, labels, mask_b, use_bg,
                                                      flag, C);
        lsa_kernel<<<BS, 64, 0, stream>>>(C, nullptr, rows_out, cols_out);
    }
}

// Round 9
// 1034.619 us; speedup vs baseline: 1.0734x; 1.0215x over previous
//
#include <hip/hip_runtime.h>
#include <hip/hip_bf16.h>
#include <math.h>

#define BS 32
#define QN 256
#define TN 128
#define NCLS 2048
#define NTGT (BS * TN)  // 4096

// ---------------------------------------------------------------------------
// Detect whether agent_mask is stored as 1-byte bools or 4-byte int32.
// ---------------------------------------------------------------------------
__global__ void detect_mask_layout(const unsigned char* __restrict__ m, int* flag) {
    __shared__ int found;
    if (threadIdx.x == 0) found = 0;
    __syncthreads();
    int local = 0;
    for (int i = threadIdx.x; i < BS * QN; i += blockDim.x) {
        if ((i & 3) != 0 && m[i] != 0) local = 1;
    }
    if (local) atomicOr(&found, 1);
    __syncthreads();
    if (threadIdx.x == 0) *flag = found;  // 1 = byte layout, 0 = int32 layout
}

// ---------------------------------------------------------------------------
// Serial prefix: softmax per row, write ONLY the block-diagonal transposed
// entries CT[b][i][q] that the solver needs. 4 MB write instead of 128 MB.
// ---------------------------------------------------------------------------
__global__ __launch_bounds__(256) void ct_kernel(
    const float* __restrict__ logits, const int* __restrict__ labels,
    const unsigned char* __restrict__ mask_b, const int* __restrict__ use_bg,
    const int* __restrict__ layout_flag, float* __restrict__ CT) {
    __shared__ float prob_sh[NCLS];
    __shared__ float red[4];

    const int tid = threadIdx.x;
    const int bq = blockIdx.x;  // b*QN + q
    const float* row = logits + (size_t)bq * NCLS;

    const float4 xa = ((const float4*)row)[tid];
    const float4 xb = ((const float4*)row)[tid + 256];

    float m = fmaxf(fmaxf(fmaxf(xa.x, xa.y), fmaxf(xa.z, xa.w)),
                    fmaxf(fmaxf(xb.x, xb.y), fmaxf(xb.z, xb.w)));
#pragma unroll
    for (int off = 32; off >= 1; off >>= 1) m = fmaxf(m, __shfl_xor(m, off));
    if ((tid & 63) == 0) red[tid >> 6] = m;
    __syncthreads();
    m = fmaxf(fmaxf(red[0], red[1]), fmaxf(red[2], red[3]));
    __syncthreads();

    float4 ea, eb;
    ea.x = expf(xa.x - m);
    ea.y = expf(xa.y - m);
    ea.z = expf(xa.z - m);
    ea.w = expf(xa.w - m);
    eb.x = expf(xb.x - m);
    eb.y = expf(xb.y - m);
    eb.z = expf(xb.z - m);
    eb.w = expf(xb.w - m);
    float s = ((ea.x + ea.y) + (ea.z + ea.w)) + ((eb.x + eb.y) + (eb.z + eb.w));
#pragma unroll
    for (int off = 32; off >= 1; off >>= 1) s += __shfl_xor(s, off);
    if ((tid & 63) == 0) red[tid >> 6] = s;
    __syncthreads();
    s = ((red[0] + red[1]) + red[2]) + red[3];

    ((float4*)prob_sh)[tid] = make_float4(ea.x / s, ea.y / s, ea.z / s, ea.w / s);
    ((float4*)prob_sh)[tid + 256] = make_float4(eb.x / s, eb.y / s, eb.z / s, eb.w / s);

    const int ub = *use_bg;
    int am;
    if (*layout_flag)
        am = mask_b[bq];
    else
        am = ((const int*)mask_b)[bq];
    const bool zero_row = (ub == 0) && (am == 0);
    __syncthreads();

    if (tid < TN) {
        const int bb = bq >> 8;   // b
        const int q = bq & 255;   // q
        const int lab = labels[bb * TN + tid];
        CT[(size_t)bb * TN * QN + (size_t)tid * QN + q] =
            zero_row ? 0.0f : -prob_sh[lab];
    }
}

// ---------------------------------------------------------------------------
// Fallback full-C kernel (used only when workspace lacks CT room).
// ---------------------------------------------------------------------------
__global__ __launch_bounds__(256) void compute_C_kernel(
    const float* __restrict__ logits, const int* __restrict__ labels,
    const unsigned char* __restrict__ mask_b, const int* __restrict__ use_bg,
    const int* __restrict__ layout_flag, float* __restrict__ C) {
    __shared__ float prob_sh[NCLS];
    __shared__ float red[4];

    const int tid = threadIdx.x;
    const int bq = blockIdx.x;
    const float* row = logits + (size_t)bq * NCLS;

    const float4 xa = ((const float4*)row)[tid];
    const float4 xb = ((const float4*)row)[tid + 256];

    float m = fmaxf(fmaxf(fmaxf(xa.x, xa.y), fmaxf(xa.z, xa.w)),
                    fmaxf(fmaxf(xb.x, xb.y), fmaxf(xb.z, xb.w)));
#pragma unroll
    for (int off = 32; off >= 1; off >>= 1) m = fmaxf(m, __shfl_xor(m, off));
    if ((tid & 63) == 0) red[tid >> 6] = m;
    __syncthreads();
    m = fmaxf(fmaxf(red[0], red[1]), fmaxf(red[2], red[3]));
    __syncthreads();

    float4 ea, eb;
    ea.x = expf(xa.x - m);
    ea.y = expf(xa.y - m);
    ea.z = expf(xa.z - m);
    ea.w = expf(xa.w - m);
    eb.x = expf(xb.x - m);
    eb.y = expf(xb.y - m);
    eb.z = expf(xb.z - m);
    eb.w = expf(xb.w - m);
    float s = ((ea.x + ea.y) + (ea.z + ea.w)) + ((eb.x + eb.y) + (eb.z + eb.w));
#pragma unroll
    for (int off = 32; off >= 1; off >>= 1) s += __shfl_xor(s, off);
    if ((tid & 63) == 0) red[tid >> 6] = s;
    __syncthreads();
    s = ((red[0] + red[1]) + red[2]) + red[3];

    ((float4*)prob_sh)[tid] = make_float4(ea.x / s, ea.y / s, ea.z / s, ea.w / s);
    ((float4*)prob_sh)[tid + 256] = make_float4(eb.x / s, eb.y / s, eb.z / s, eb.w / s);

    const int ub = *use_bg;
    int am;
    if (*layout_flag)
        am = mask_b[bq];
    else
        am = ((const int*)mask_b)[bq];
    const bool zero_row = (ub == 0) && (am == 0);
    __syncthreads();

    float* Crow = C + (size_t)bq * NTGT;
    const int4* lab4 = (const int4*)labels;
    if (zero_row) {
        const float4 z = make_float4(0.f, 0.f, 0.f, 0.f);
#pragma unroll
        for (int k = 0; k < 4; k++) ((float4*)Crow)[tid + k * 256] = z;
    } else {
#pragma unroll
        for (int k = 0; k < 4; k++) {
            const int4 l = lab4[tid + k * 256];
            float4 o;
            o.x = -prob_sh[l.x];
            o.y = -prob_sh[l.y];
            o.z = -prob_sh[l.z];
            o.w = -prob_sh[l.w];
            ((float4*)Crow)[tid + k * 256] = o;
        }
    }
}

// ---------------------------------------------------------------------------
// Cross-lane helpers.
// ---------------------------------------------------------------------------
template <int CTRL>
__device__ __forceinline__ double dpp_mov_f64(double x) {
    union { double d; int i[2]; } a, r;
    a.d = x;
    r.i[0] = __builtin_amdgcn_update_dpp(0, a.i[0], CTRL, 0xF, 0xF, true);
    r.i[1] = __builtin_amdgcn_update_dpp(0, a.i[1], CTRL, 0xF, 0xF, true);
    return r.d;
}
__device__ __forceinline__ double read_lane_f64(double x, int srclane) {
    union { double d; int i[2]; } a, r;
    a.d = x;
    r.i[0] = __builtin_amdgcn_readlane(a.i[0], srclane);
    r.i[1] = __builtin_amdgcn_readlane(a.i[1], srclane);
    return r.d;
}

#define QUAD_XOR1 0xB1   // quad_perm(1,0,3,2)
#define QUAD_XOR2 0x4E   // quad_perm(2,3,0,1)
#define ROW_ROR4  0x124  // row_ror:4
#define ROW_ROR8  0x128  // row_ror:8

// ---------------------------------------------------------------------------
// Jonker-Volgenant, exact replica of reference _lsa() on the transposed
// problem (nr=TN=128 rows=targets, nc=QN=256 cols=queries). One wave/batch.
//
// Base = round-8 known-good (890us): tie-mask selection (2 ballots/pop),
// packed-pk row4col readlane, register augment walk, 4-readlane reduce finish.
//
// Round-9 deltas (mechanism-coupled package, shortens the post-LDS ca chain
// 3 dependent f64 ops -> 1):
//  1. u duals: LDS -> register mirrors + readlane. ui is ready ~16cy after
//     krc, ~100cy before cc lands (LDS returns are in-order, so an LDS ui
//     always lands AFTER cc and blocks any reassociation -- this is why the
//     fold requires register u). Round loop now has ZERO LDS ops besides the
//     cost-row read; per-round __syncthreads deleted (single-wave block).
//  2. v-fold: s2 = ui - m_d and wj = vj + s2 computed DURING the 120cy LDS
//     flight (off-chain); ca = cc - wj is ONE dependent op after cc.
//     Exact-tie classes preserved bit-exactly: zero-cost edges (0+x, x-0,
//     exact negation identities) and identical-operand-tuple ties (duplicate
//     labels) compute identically in both orders; those are the only
//     systematic tie classes (cross-tuple sub-ulp ties are measure-zero).
//  3. Cross-round prefetch of row cur+1 (deterministic address, demand
//     semantics) issued before the register-only augment walk.
//
// [r1/r4: do NOT retry in-loop speculative LDS prefetch. r5: do NOT exceed
//  2 ballots/pop. r7: do NOT add dependent DPP bcast stages to the reduce
//  finish (that bundle's -25us was the DPP finish; u-readlane was neutral
//  under the old op order and only pays combined with the fold).]
// ---------------------------------------------------------------------------
__device__ __forceinline__ void lsa_solve(
    const float* __restrict__ C, const float* __restrict__ CT,
    float* __restrict__ rows_out, float* __restrict__ cols_out,
    int b, int lane,
    float* cost_sh, int* col4row_sh) {
    const int j0 = lane * 4;

    double v0 = 0.0, v1 = 0.0, v2 = 0.0, v3 = 0.0;  // col duals (owned cols)
    double u0 = 0.0, u1 = 0.0;                      // row duals (owned rows 2l,2l+1)
    unsigned pk = 0u;       // packed row4col+1 (byte per owned col); 0 = -1
    int c0 = -1, c1 = -1;   // col4row (owned rows)

    if (CT) {
        const float4* src = (const float4*)(CT + (size_t)b * TN * QN);
        float4* dst = (float4*)cost_sh;
#pragma unroll 8
        for (int it = 0; it < TN * QN / 4 / 64; it++) {
            const int idx = it * 64 + lane;
            dst[idx] = src[idx];
        }
    } else {
        // fallback: scattered gather straight from C (one-time staging cost)
        const float* cbsrc = C + (size_t)b * QN * NTGT + b * TN;
        for (int it = 0; it < 512; it++) {
            const int j = it >> 1;
            const int i = lane + 64 * (it & 1);
            cost_sh[i * QN + j] = cbsrc[(size_t)j * NTGT + i];
        }
    }
    __syncthreads();

    float4 nx_cc = *(const float4*)(cost_sh + j0);  // row 0 prefetch

    for (int cur = 0; cur < TN; cur++) {
        double dv0 = INFINITY, dv1 = INFINITY, dv2 = INFINITY, dv3 = INFINITY;
        double dm0 = INFINITY, dm1 = INFINITY, dm2 = INFINITY, dm3 = INFINITY;
        double du0 = 0.0, du1 = 0.0;
        int sc = 0, sr = 0;
        int p0 = 0, p1 = 0, p2 = 0, p3 = 0;
        if (lane == (cur >> 1)) sr = 1 << (cur & 1);  // SR[cur]=1

        int i = cur;
        double m_d = 0.0;
        float4 cc = nx_cc;  // prefetched during previous round's walk
        // s2 = u[i] - m_d  (m_d = 0 at round start; x - 0 == x exactly)
        double s2 = read_lane_f64((cur & 1) ? u1 : u0, cur >> 1);
        int tm = 0;  // tie mask: owned cols with d == m_d, not SC'd
        int sink;

        while (true) {
            // folded duals: w = v + (u[i] - m_d), computed during LDS flight
            const double w0 = v0 + s2;
            const double w1 = v1 + s2;
            const double w2 = v2 + s2;
            const double w3 = v3 + s2;
            // ca = cost - w  ==  ((m_d + cost) - u[i]) - v  (exact algebra;
            // bit-exact on all systematic tie classes, see header)
            const double ca0 = (double)cc.x - w0;
            const double ca1 = (double)cc.y - w1;
            const double ca2 = (double)cc.z - w2;
            const double ca3 = (double)cc.w - w3;
            const bool i0 = !(sc & 1) && (ca0 < dv0);
            const bool i1 = !(sc & 2) && (ca1 < dv1);
            const bool i2 = !(sc & 4) && (ca2 < dv2);
            const bool i3 = !(sc & 8) && (ca3 < dv3);
            if (i0) { dv0 = ca0; dm0 = ca0; p0 = i; }
            if (i1) { dv1 = ca1; dm1 = ca1; p1 = i; }
            if (i2) { dv2 = ca2; dm2 = ca2; p2 = i; }
            if (i3) { dv3 = ca3; dm3 = ca3; p3 = i; }

            // lane-local tie maintenance (VALU, 2 ballots total per pop)
            const bool lt_any = (i0 && ca0 < m_d) || (i1 && ca1 < m_d) ||
                                (i2 && ca2 < m_d) || (i3 && ca3 < m_d);
            int tmn = tm;
            if (i0 && ca0 == m_d) tmn |= 1;
            if (i1 && ca1 == m_d) tmn |= 2;
            if (i2 && ca2 == m_d) tmn |= 4;
            if (i3 && ca3 == m_d) tmn |= 8;

            const unsigned long long LT = __ballot(lt_any);
            unsigned long long W = __ballot(tmn != 0);

            if (LT != 0ull || W == 0ull) {
                // full argmin: f64 min tree (4 DPP row stages + readlane finish)
                double lm = fmin(fmin(dm0, dm1), fmin(dm2, dm3));
                lm = fmin(lm, dpp_mov_f64<QUAD_XOR1>(lm));
                lm = fmin(lm, dpp_mov_f64<QUAD_XOR2>(lm));
                lm = fmin(lm, dpp_mov_f64<ROW_ROR4>(lm));
                lm = fmin(lm, dpp_mov_f64<ROW_ROR8>(lm));
                const double r0 = read_lane_f64(lm, 0);
                const double r1 = read_lane_f64(lm, 16);
                const double r2 = read_lane_f64(lm, 32);
                const double r3 = read_lane_f64(lm, 48);
                m_d = fmin(fmin(r0, r1), fmin(r2, r3));
                // rebuild tie mask (dm=INF for SC'd -> excluded automatically)
                tmn = (dm0 == m_d ? 1 : 0) | (dm1 == m_d ? 2 : 0) |
                      (dm2 == m_d ? 4 : 0) | (dm3 == m_d ? 8 : 0);
                W = __ballot(tmn != 0);
            }

            // pick lowest column among ties: lowest lane, then lowest slot.
            // The two readlanes are independent -> issue back-to-back.
            const int owner = __ffsll((unsigned long long)W) - 1;
            const int sm = __builtin_amdgcn_readlane(tmn, owner);
            const unsigned pkv = (unsigned)__builtin_amdgcn_readlane((int)pk, owner);
            const int slot = __ffs(sm) - 1;
            const int jmin = (owner << 2) + slot;
            const int krc = (int)((pkv >> (slot * 8)) & 0xffu) - 1;

            if (lane == owner) {  // mark SC, freeze dm, clear tie bit
                sc |= 1 << slot;
                tmn &= ~(1 << slot);
                if (slot == 0) dm0 = INFINITY;
                else if (slot == 1) dm1 = INFINITY;
                else if (slot == 2) dm2 = INFINITY;
                else dm3 = INFINITY;
            }
            tm = tmn;

            if (krc < 0) { sink = jmin; break; }

            // demand load of the next row; ui/s2/w computed under its flight
            cc = *(const float4*)(cost_sh + krc * QN + j0);
            const double ui = read_lane_f64((krc & 1) ? u1 : u0, krc >> 1);
            s2 = ui - m_d;

            // SR/du row mirrors
            if (lane == (krc >> 1)) {
                if (krc & 1) { du1 = m_d; sr |= 2; }
                else { du0 = m_d; sr |= 1; }
            }
            i = krc;
        }

        // ---- round end (registers only; zero LDS, zero barriers) ----
        // dual updates (scipy _lsap_body); dv/du frozen at selection time
        if (sc & 1) v0 -= m_d - dv0;
        if (sc & 2) v1 -= m_d - dv1;
        if (sc & 4) v2 -= m_d - dv2;
        if (sc & 8) v3 -= m_d - dv3;
        if (sr & 1) u0 += (2 * lane == cur) ? m_d : (m_d - du0);
        if (sr & 2) u1 += (2 * lane + 1 == cur) ? m_d : (m_d - du1);

        // prefetch next round's first row; latency hides under the walk
        if (cur + 1 < TN) nx_cc = *(const float4*)(cost_sh + (cur + 1) * QN + j0);

        // augment along shortest path: all lanes walk redundantly (uniform),
        // each updating its own register mirrors via readlane broadcasts.
        // pk (packed row4col) is updated HERE only -- off the pop chain.
        int j = sink;
        while (true) {
            const int sl = j & 3;
            const int ow = j >> 2;
            const int pa = (sl & 1) ? p1 : p0;
            const int pb = (sl & 1) ? p3 : p2;
            const int pi = __builtin_amdgcn_readlane((sl & 2) ? pb : pa, ow);
            if (lane == ow) {  // row4col[j] = pi  (packed byte insert)
                const int sh = sl * 8;
                pk = (pk & ~(0xffu << sh)) | ((unsigned)(pi + 1) << sh);
            }
            const int nj = __builtin_amdgcn_readlane((pi & 1) ? c1 : c0, pi >> 1);
            if (lane == (pi >> 1)) {  // col4row[pi] = j
                if (pi & 1) c1 = j;
                else c0 = j;
            }
            j = nj;
            if (pi == cur) break;
        }
    }

    // publish col4row once for the rank pass
    col4row_sh[2 * lane] = c0;
    col4row_sh[2 * lane + 1] = c1;
    __syncthreads();

    // transposed output: rank by col4row value (values distinct)
#pragma unroll
    for (int t = 0; t < 2; t++) {
        const int ii = lane + 64 * t;
        const int myv = col4row_sh[ii];
        int rank = 0;
        for (int t2 = 0; t2 < TN; t2++) rank += (col4row_sh[t2] < myv) ? 1 : 0;
        rows_out[b * TN + rank] = (float)myv;
        cols_out[b * TN + rank] = (float)ii;
    }
}

// ---------------------------------------------------------------------------
// Standalone lsa kernel (fallback path).
// ---------------------------------------------------------------------------
__global__ __launch_bounds__(64) void lsa_kernel(const float* __restrict__ C,
                                                 const float* __restrict__ CT,
                                                 float* __restrict__ rows_out,
                                                 float* __restrict__ cols_out) {
    __shared__ float cost_sh[TN * QN];  // 128 KB
    __shared__ int col4row_sh[TN];
    lsa_solve(C, CT, rows_out, cols_out, blockIdx.x, threadIdx.x,
              cost_sh, col4row_sh);
}

// ---------------------------------------------------------------------------
// Fused kernel: blocks 0..BS-1 run the solver (1 wave, 1 CU each, LDS-pinned
// so no filler can co-reside: 2x~129KB > 160KB). Blocks BS.. are fillers
// that produce the 128 MB C output on the other ~224 CUs, fully hidden under
// the solve. No inter-block deps: disjoint outputs, read-only inputs.
// ---------------------------------------------------------------------------
__global__ __launch_bounds__(64) void fused_kernel(
    const float* __restrict__ logits, const int* __restrict__ labels,
    const unsigned char* __restrict__ mask_b, const int* __restrict__ use_bg,
    const int* __restrict__ layout_flag, const float* __restrict__ CT,
    float* __restrict__ C, float* __restrict__ rows_out,
    float* __restrict__ cols_out) {
    __shared__ float cost_sh[TN * QN];  // solver: cost matrix; filler: prob scratch
    __shared__ int col4row_sh[TN];

    const int lane = threadIdx.x;

    if (blockIdx.x >= BS) {
        // ---------------- filler: one row of C per block, wave-local ----------------
        const int bq = blockIdx.x - BS;
        const float* row = logits + (size_t)bq * NCLS;

        float4 x[8];
#pragma unroll
        for (int k = 0; k < 8; k++) x[k] = ((const float4*)row)[lane + 64 * k];

        float m = -INFINITY;
#pragma unroll
        for (int k = 0; k < 8; k++)
            m = fmaxf(m, fmaxf(fmaxf(x[k].x, x[k].y), fmaxf(x[k].z, x[k].w)));
#pragma unroll
        for (int off = 32; off >= 1; off >>= 1) m = fmaxf(m, __shfl_xor(m, off));

        float s = 0.f;
        float4 e[8];
#pragma unroll
        for (int k = 0; k < 8; k++) {
            e[k].x = expf(x[k].x - m);
            e[k].y = expf(x[k].y - m);
            e[k].z = expf(x[k].z - m);
            e[k].w = expf(x[k].w - m);
            s += ((e[k].x + e[k].y) + (e[k].z + e[k].w));
        }
#pragma unroll
        for (int off = 32; off >= 1; off >>= 1) s += __shfl_xor(s, off);

        float* prob = cost_sh;  // 8 KB scratch
#pragma unroll
        for (int k = 0; k < 8; k++)
            ((float4*)prob)[lane + 64 * k] =
                make_float4(e[k].x / s, e[k].y / s, e[k].z / s, e[k].w / s);

        const int ub = *use_bg;
        int am;
        if (*layout_flag)
            am = mask_b[bq];
        else
            am = ((const int*)mask_b)[bq];
        const bool zero_row = (ub == 0) && (am == 0);
        __syncthreads();  // single wave: cheap lgkmcnt drain + barrier

        float* Crow = C + (size_t)bq * NTGT;
        const int4* lab4 = (const int4*)labels;
        if (zero_row) {
            const float4 z = make_float4(0.f, 0.f, 0.f, 0.f);
#pragma unroll
            for (int k = 0; k < 16; k++) ((float4*)Crow)[lane + 64 * k] = z;
        } else {
#pragma unroll
            for (int k = 0; k < 16; k++) {
                const int4 l = lab4[lane + 64 * k];
                ((float4*)Crow)[lane + 64 * k] =
                    make_float4(-prob[l.x], -prob[l.y], -prob[l.z], -prob[l.w]);
            }
        }
        return;
    }

    // ---------------- solver ----------------
    lsa_solve(nullptr, CT, rows_out, cols_out, blockIdx.x, lane,
              cost_sh, col4row_sh);
}

extern "C" void kernel_launch(void* const* d_in, const int* in_sizes, int n_in,
                              void* d_out, int out_size, void* d_ws, size_t ws_size,
                              hipStream_t stream) {
    const float* logits = (const float*)d_in[0];                  // [32,256,2048] f32
    const int* labels = (const int*)d_in[1];                      // [32,128] i32
    const unsigned char* mask_b = (const unsigned char*)d_in[2];  // [32,256] bool/i32
    const int* use_bg = (const int*)d_in[3];                      // scalar

    float* C = (float*)d_out;  // 32*256*4096
    float* rows_out = C + (size_t)BS * QN * NTGT;
    float* cols_out = rows_out + BS * TN;

    int* flag = (int*)d_ws;
    const size_t ct_off = 4096;
    const size_t ct_bytes = (size_t)BS * TN * QN * sizeof(float);  // 4 MB
    const bool useCT = ws_size >= ct_off + ct_bytes;
    float* CT = useCT ? (float*)((char*)d_ws + ct_off) : nullptr;

    detect_mask_layout<<<1, 256, 0, stream>>>(mask_b, flag);
    if (useCT) {
        // minimal serial prefix (4 MB CT), then solver + hidden C production
        ct_kernel<<<BS * QN, 256, 0, stream>>>(logits, labels, mask_b, use_bg, flag, CT);
        fused_kernel<<<BS + BS * QN, 64, 0, stream>>>(logits, labels, mask_b, use_bg,
                                                      flag, CT, C, rows_out, cols_out);
    } else {
        compute_C_kernel<<<BS * QN, 256, 0, stream>>>(logits, labels, mask_b, use_bg,
                                                      flag, C);
        lsa_kernel<<<BS, 64, 0, stream>>>(C, nullptr, rows_out, cols_out);
    }
}